// Round 1
// baseline (73.499 us; speedup 1.0000x reference)
//
#include <hip/hip_runtime.h>

#define BN_EPS 1e-5f
#define NEG_SLOPE 0.2f

constexpr int B_ = 16384;
constexpr int Din = 4096;
constexpr int Dout = 256;
constexpr int D_RANK = 20;

// ws layout (floats):
// [0, 4096)        : Bv
// [4096, 4352)     : A
// [4352, 20736)    : t (16384)
// [20736, 20992)   : s (256)  = A*gamma*rsqrt(A^2*var+eps)
// [20992]          : mean_t
#define WS_BV 0
#define WS_A 4096
#define WS_T 4352
#define WS_S 20736
#define WS_MEAN 20992

// ---------------- Kernel 1: synthesize A (Dout) and Bv (Din) -----------------
// grid = 1 + Din/256 blocks, 256 threads.
// block 0: A[j] = sum_d alphas[d] * controls_A[d][j]   (coalesced over j)
// blocks 1..: Bv[k] = sum_d alphas[d] * controls_B[k][d]
__global__ __launch_bounds__(256) void k_synth(
    const float* __restrict__ alphas, const float* __restrict__ cA,
    const float* __restrict__ cB, float* __restrict__ A, float* __restrict__ Bv) {
  __shared__ float al[D_RANK];
  int tid = threadIdx.x;
  if (tid < D_RANK) al[tid] = alphas[tid];
  __syncthreads();
  if (blockIdx.x == 0) {
    float s = 0.f;
#pragma unroll
    for (int d = 0; d < D_RANK; ++d) s += al[d] * cA[d * Dout + tid];
    A[tid] = s;
  } else {
    int k = (blockIdx.x - 1) * 256 + tid;
    float s = 0.f;
#pragma unroll
    for (int d = 0; d < D_RANK; ++d) s += al[d] * cB[k * D_RANK + d];
    Bv[k] = s;
  }
}

// ---------------- Kernel 2: t = x @ Bv (the memory-bound pass) ---------------
// one wave per row; 4 waves (256 threads) per block; float4 loads.
__global__ __launch_bounds__(256) void k_matvec(
    const float* __restrict__ x, const float* __restrict__ Bv,
    float* __restrict__ t) {
  int wave = threadIdx.x >> 6;
  int lane = threadIdx.x & 63;
  int row = blockIdx.x * 4 + wave;
  const float4* xr = reinterpret_cast<const float4*>(x + (size_t)row * Din);
  const float4* bv = reinterpret_cast<const float4*>(Bv);
  float acc = 0.f;
#pragma unroll
  for (int it = 0; it < (Din / 4) / 64; ++it) {  // 16 iters
    float4 xv = xr[it * 64 + lane];
    float4 bw = bv[it * 64 + lane];   // 16 KiB, L1-resident
    acc += xv.x * bw.x + xv.y * bw.y + xv.z * bw.z + xv.w * bw.w;
  }
#pragma unroll
  for (int off = 32; off > 0; off >>= 1) acc += __shfl_down(acc, off, 64);
  if (lane == 0) t[row] = acc;
}

// ---------------- Kernel 3: stats of t + per-column scale --------------------
// single block, 256 threads. Deterministic tree reduction in double.
__global__ __launch_bounds__(256) void k_stats(
    const float* __restrict__ t, const float* __restrict__ A,
    const float* __restrict__ gamma, float* __restrict__ s,
    float* __restrict__ meanp) {
  __shared__ double sd[256];
  __shared__ double sq[256];
  int tid = threadIdx.x;
  double ls = 0.0, lq = 0.0;
  for (int i = tid; i < B_; i += 256) {
    double v = (double)t[i];
    ls += v;
    lq += v * v;
  }
  sd[tid] = ls;
  sq[tid] = lq;
  __syncthreads();
  for (int off = 128; off > 0; off >>= 1) {
    if (tid < off) {
      sd[tid] += sd[tid + off];
      sq[tid] += sq[tid + off];
    }
    __syncthreads();
  }
  double mean = sd[0] / (double)B_;
  double var = sq[0] / (double)B_ - mean * mean;  // biased, matches jnp.var
  float a = A[tid];
  double varj = (double)a * (double)a * var;
  float inv = rsqrtf((float)varj + BN_EPS);
  s[tid] = a * gamma[tid] * inv;
  if (tid == 0) *meanp = (float)mean;
}

// ---------------- Kernel 4: write out = leaky((t[i]-m)*s[j] + beta[j]) ------
// 4 rows per 256-thread block; each thread writes one float4 (coalesced).
__global__ __launch_bounds__(256) void k_out(
    const float* __restrict__ t, const float* __restrict__ s,
    const float* __restrict__ beta, const float* __restrict__ meanp,
    float* __restrict__ out) {
  __shared__ float ss[Dout];
  __shared__ float bs[Dout];
  int tid = threadIdx.x;
  ss[tid] = s[tid];
  bs[tid] = beta[tid];
  __syncthreads();
  float mean = *meanp;
  int r = tid >> 6;          // 0..3 (row within block)
  int c4 = (tid & 63);       // float4 index within row (64 * 4 = 256 cols)
  int row = blockIdx.x * 4 + r;
  float tv = t[row] - mean;
  float4 sv = *reinterpret_cast<const float4*>(&ss[c4 * 4]);
  float4 bv = *reinterpret_cast<const float4*>(&bs[c4 * 4]);
  float4 o;
  o.x = tv * sv.x + bv.x; o.x = (o.x >= 0.f) ? o.x : NEG_SLOPE * o.x;
  o.y = tv * sv.y + bv.y; o.y = (o.y >= 0.f) ? o.y : NEG_SLOPE * o.y;
  o.z = tv * sv.z + bv.z; o.z = (o.z >= 0.f) ? o.z : NEG_SLOPE * o.z;
  o.w = tv * sv.w + bv.w; o.w = (o.w >= 0.f) ? o.w : NEG_SLOPE * o.w;
  reinterpret_cast<float4*>(out)[(size_t)row * (Dout / 4) + c4] = o;
}

extern "C" void kernel_launch(void* const* d_in, const int* in_sizes, int n_in,
                              void* d_out, int out_size, void* d_ws, size_t ws_size,
                              hipStream_t stream) {
  const float* x      = (const float*)d_in[0];
  const float* alphas = (const float*)d_in[1];
  const float* cA     = (const float*)d_in[2];
  const float* cB     = (const float*)d_in[3];
  // d_in[4] = linear_bias: cancels exactly inside BatchNorm (out - mean).
  const float* gamma  = (const float*)d_in[5];
  const float* beta   = (const float*)d_in[6];
  float* out = (float*)d_out;
  float* ws  = (float*)d_ws;

  float* Bv   = ws + WS_BV;
  float* A    = ws + WS_A;
  float* t    = ws + WS_T;
  float* s    = ws + WS_S;
  float* mean = ws + WS_MEAN;

  k_synth<<<1 + Din / 256, 256, 0, stream>>>(alphas, cA, cB, A, Bv);
  k_matvec<<<B_ / 4, 256, 0, stream>>>(x, Bv, t);
  k_stats<<<1, 256, 0, stream>>>(t, A, gamma, s, mean);
  k_out<<<B_ / 4, 256, 0, stream>>>(t, s, beta, mean, out);
}

// Round 2
// 64.868 us; speedup vs baseline: 1.1331x; 1.1331x over previous
//
#include <hip/hip_runtime.h>

#define BN_EPS 1e-5f
#define NEG_SLOPE 0.2f

constexpr int B_ = 16384;
constexpr int Din = 4096;
constexpr int Dout = 256;
constexpr int D_RANK = 20;

// ws layout (floats):
// [0, 4096)        : Bv
// [4096, 4352)     : A
// [4352, 20736)    : t (16384)
// [20736, 24832)   : partials: 1024 x double2 (byte off 82944, 16B-aligned)
#define WS_BV 0
#define WS_A 4096
#define WS_T 4352
#define WS_PART 20736

// ---------------- Kernel 1: synthesize A (Dout) and Bv (Din) -----------------
__global__ __launch_bounds__(256) void k_synth(
    const float* __restrict__ alphas, const float* __restrict__ cA,
    const float* __restrict__ cB, float* __restrict__ A, float* __restrict__ Bv) {
  __shared__ float al[D_RANK];
  int tid = threadIdx.x;
  if (tid < D_RANK) al[tid] = alphas[tid];
  __syncthreads();
  if (blockIdx.x == 0) {
    float s = 0.f;
#pragma unroll
    for (int d = 0; d < D_RANK; ++d) s += al[d] * cA[d * Dout + tid];
    A[tid] = s;
  } else {
    int k = (blockIdx.x - 1) * 256 + tid;
    float s = 0.f;
#pragma unroll
    for (int d = 0; d < D_RANK; ++d) s += al[d] * cB[k * D_RANK + d];
    Bv[k] = s;
  }
}

// ---------------- Kernel 2: t = x @ Bv + per-block (sum, sumsq) partial ------
// 1024 threads = 16 waves, one row per wave. grid = B_/16 = 1024.
__global__ __launch_bounds__(1024) void k_matvec(
    const float* __restrict__ x, const float* __restrict__ Bv,
    float* __restrict__ t, double2* __restrict__ partials) {
  int wave = threadIdx.x >> 6;   // 0..15
  int lane = threadIdx.x & 63;
  int row = blockIdx.x * 16 + wave;
  const float4* xr = reinterpret_cast<const float4*>(x + (size_t)row * Din);
  const float4* bv = reinterpret_cast<const float4*>(Bv);
  float acc0 = 0.f, acc1 = 0.f;
#pragma unroll
  for (int it = 0; it < 8; ++it) {
    float4 xa = xr[it * 128 + lane];
    float4 xb = xr[it * 128 + 64 + lane];
    float4 ba = bv[it * 128 + lane];        // 16 KiB, L1-resident
    float4 bb = bv[it * 128 + 64 + lane];
    acc0 += xa.x * ba.x + xa.y * ba.y + xa.z * ba.z + xa.w * ba.w;
    acc1 += xb.x * bb.x + xb.y * bb.y + xb.z * bb.z + xb.w * bb.w;
  }
  float acc = acc0 + acc1;
#pragma unroll
  for (int off = 32; off > 0; off >>= 1) acc += __shfl_down(acc, off, 64);
  __shared__ float tv[16];
  if (lane == 0) {
    t[row] = acc;
    tv[wave] = acc;
  }
  __syncthreads();
  if (threadIdx.x == 0) {
    double s = 0.0, q = 0.0;
#pragma unroll
    for (int w = 0; w < 16; ++w) {
      double v = (double)tv[w];
      s += v;
      q += v * v;
    }
    partials[blockIdx.x] = make_double2(s, q);
  }
}

// ---------------- Kernel 3: finish = reduce partials + BN + leaky + write ----
// grid = B_/4 = 4096 blocks x 256 threads. Each block redundantly reduces the
// 1024 double2 partials (8 KiB, L2-hot), then writes 4 output rows.
// Fixed tree order -> deterministic.
__global__ __launch_bounds__(256) void k_finish(
    const float* __restrict__ t, const double2* __restrict__ partials,
    const float* __restrict__ A, const float* __restrict__ gamma,
    const float* __restrict__ beta, float* __restrict__ out) {
  __shared__ double sd[256];
  __shared__ double sq[256];
  int tid = threadIdx.x;
  double ls = 0.0, lq = 0.0;
#pragma unroll
  for (int i = 0; i < 4; ++i) {
    double2 p = partials[tid + i * 256];
    ls += p.x;
    lq += p.y;
  }
  sd[tid] = ls;
  sq[tid] = lq;
  __syncthreads();
  for (int off = 128; off > 0; off >>= 1) {
    if (tid < off) {
      sd[tid] += sd[tid + off];
      sq[tid] += sq[tid + off];
    }
    __syncthreads();
  }
  double mean = sd[0] / (double)B_;
  double var = sq[0] / (double)B_ - mean * mean;  // biased, matches jnp.var
  float a = A[tid];
  float inv = rsqrtf((float)((double)a * (double)a * var) + BN_EPS);
  __shared__ float ss[Dout];
  __shared__ float bs[Dout];
  __shared__ float ts[4];
  ss[tid] = a * gamma[tid] * inv;
  bs[tid] = beta[tid];
  if (tid < 4) ts[tid] = t[blockIdx.x * 4 + tid];
  __syncthreads();
  float m = (float)mean;
  int r = tid >> 6;      // row within block (0..3)
  int c4 = tid & 63;     // float4 col index (64*4 = 256)
  int row = blockIdx.x * 4 + r;
  float tvv = ts[r] - m;
  float4 sv = *reinterpret_cast<const float4*>(&ss[c4 * 4]);
  float4 bv = *reinterpret_cast<const float4*>(&bs[c4 * 4]);
  float4 o;
  o.x = tvv * sv.x + bv.x; o.x = (o.x >= 0.f) ? o.x : NEG_SLOPE * o.x;
  o.y = tvv * sv.y + bv.y; o.y = (o.y >= 0.f) ? o.y : NEG_SLOPE * o.y;
  o.z = tvv * sv.z + bv.z; o.z = (o.z >= 0.f) ? o.z : NEG_SLOPE * o.z;
  o.w = tvv * sv.w + bv.w; o.w = (o.w >= 0.f) ? o.w : NEG_SLOPE * o.w;
  reinterpret_cast<float4*>(out)[(size_t)row * (Dout / 4) + c4] = o;
}

extern "C" void kernel_launch(void* const* d_in, const int* in_sizes, int n_in,
                              void* d_out, int out_size, void* d_ws, size_t ws_size,
                              hipStream_t stream) {
  const float* x      = (const float*)d_in[0];
  const float* alphas = (const float*)d_in[1];
  const float* cA     = (const float*)d_in[2];
  const float* cB     = (const float*)d_in[3];
  // d_in[4] = linear_bias: cancels exactly inside BatchNorm (out - mean).
  const float* gamma  = (const float*)d_in[5];
  const float* beta   = (const float*)d_in[6];
  float* out = (float*)d_out;
  float* ws  = (float*)d_ws;

  float*   Bv       = ws + WS_BV;
  float*   A        = ws + WS_A;
  float*   t        = ws + WS_T;
  double2* partials = reinterpret_cast<double2*>(ws + WS_PART);

  k_synth<<<1 + Din / 256, 256, 0, stream>>>(alphas, cA, cB, A, Bv);
  k_matvec<<<B_ / 16, 1024, 0, stream>>>(x, Bv, t, partials);
  k_finish<<<B_ / 4, 256, 0, stream>>>(t, partials, A, gamma, beta, out);
}

// Round 4
// 60.545 us; speedup vs baseline: 1.2140x; 1.0714x over previous
//
#include <hip/hip_runtime.h>

#define BN_EPS 1e-5f
#define NEG_SLOPE 0.2f

constexpr int B_ = 16384;
constexpr int Din = 4096;
constexpr int Dout = 256;
constexpr int D_RANK = 20;
constexpr int NPART = 2048;   // one partial per matvec block

typedef float f4 __attribute__((ext_vector_type(4)));  // native vec type: ok for nontemporal builtins

// ws layout (floats):
// [0, 4096)        : Bv
// [4096, 4352)     : A
// [4352, 20736)    : t (16384)
// [20736, ...)     : partials: 2048 x double2 (byte off 82944, 16B-aligned)
#define WS_BV 0
#define WS_A 4096
#define WS_T 4352
#define WS_PART 20736

// ---------------- Kernel 1: synthesize A (Dout) and Bv (Din) -----------------
__global__ __launch_bounds__(256) void k_synth(
    const float* __restrict__ alphas, const float* __restrict__ cA,
    const float* __restrict__ cB, float* __restrict__ A, float* __restrict__ Bv) {
  __shared__ float al[D_RANK];
  int tid = threadIdx.x;
  if (tid < D_RANK) al[tid] = alphas[tid];
  __syncthreads();
  if (blockIdx.x == 0) {
    float s = 0.f;
#pragma unroll
    for (int d = 0; d < D_RANK; ++d) s += al[d] * cA[d * Dout + tid];
    A[tid] = s;
  } else {
    int k = (blockIdx.x - 1) * 256 + tid;
    float s = 0.f;
#pragma unroll
    for (int d = 0; d < D_RANK; ++d) s += al[d] * cB[k * D_RANK + d];
    Bv[k] = s;
  }
}

// ---------------- Kernel 2: t = x @ Bv + per-block (sum, sumsq) partial ------
// 512 threads = 8 waves, one row per wave. grid = B_/8 = 2048.
// Bv staged in LDS: x is the ONLY VMEM stream (max outstanding-load depth).
__global__ __launch_bounds__(512) void k_matvec(
    const float* __restrict__ x, const float* __restrict__ Bv,
    float* __restrict__ t, double2* __restrict__ partials) {
  __shared__ f4 bvs[Din / 4];   // 16 KiB
  int tid = threadIdx.x;
  const f4* bv = reinterpret_cast<const f4*>(Bv);
  bvs[tid] = bv[tid];
  bvs[tid + 512] = bv[tid + 512];
  __syncthreads();

  int wave = tid >> 6;   // 0..7
  int lane = tid & 63;
  int row = blockIdx.x * 8 + wave;
  const f4* xr = reinterpret_cast<const f4*>(x + (size_t)row * Din);
  float acc0 = 0.f, acc1 = 0.f;
#pragma unroll
  for (int it = 0; it < 8; ++it) {
    f4 xa = __builtin_nontemporal_load(&xr[it * 128 + lane]);
    f4 xb = __builtin_nontemporal_load(&xr[it * 128 + 64 + lane]);
    f4 ba = bvs[it * 128 + lane];
    f4 bb = bvs[it * 128 + 64 + lane];
    acc0 += xa.x * ba.x + xa.y * ba.y + xa.z * ba.z + xa.w * ba.w;
    acc1 += xb.x * bb.x + xb.y * bb.y + xb.z * bb.z + xb.w * bb.w;
  }
  float acc = acc0 + acc1;
#pragma unroll
  for (int off = 32; off > 0; off >>= 1) acc += __shfl_down(acc, off, 64);
  __shared__ float tv[8];
  if (lane == 0) {
    t[row] = acc;
    tv[wave] = acc;
  }
  __syncthreads();
  if (tid == 0) {
    double s = 0.0, q = 0.0;
#pragma unroll
    for (int w = 0; w < 8; ++w) {
      double v = (double)tv[w];
      s += v;
      q += v * v;
    }
    partials[blockIdx.x] = make_double2(s, q);
  }
}

// ---------------- Kernel 3: finish = reduce partials + BN + leaky + write ----
// grid = B_/4 = 4096 blocks x 256 threads. Each block redundantly reduces the
// 2048 double2 partials (32 KiB, L2-hot), then writes 4 output rows.
// Fixed tree order -> deterministic.
__global__ __launch_bounds__(256) void k_finish(
    const float* __restrict__ t, const double2* __restrict__ partials,
    const float* __restrict__ A, const float* __restrict__ gamma,
    const float* __restrict__ beta, float* __restrict__ out) {
  __shared__ double sd[256];
  __shared__ double sq[256];
  int tid = threadIdx.x;
  double ls = 0.0, lq = 0.0;
#pragma unroll
  for (int i = 0; i < NPART / 256; ++i) {
    double2 p = partials[tid + i * 256];
    ls += p.x;
    lq += p.y;
  }
  sd[tid] = ls;
  sq[tid] = lq;
  __syncthreads();
  for (int off = 128; off > 0; off >>= 1) {
    if (tid < off) {
      sd[tid] += sd[tid + off];
      sq[tid] += sq[tid + off];
    }
    __syncthreads();
  }
  double mean = sd[0] / (double)B_;
  double var = sq[0] / (double)B_ - mean * mean;  // biased, matches jnp.var
  float a = A[tid];
  float inv = rsqrtf((float)((double)a * (double)a * var) + BN_EPS);
  __shared__ float ss[Dout];
  __shared__ float bs[Dout];
  __shared__ float ts[4];
  ss[tid] = a * gamma[tid] * inv;
  bs[tid] = beta[tid];
  if (tid < 4) ts[tid] = t[blockIdx.x * 4 + tid];
  __syncthreads();
  float m = (float)mean;
  int r = tid >> 6;      // row within block (0..3)
  int c4 = tid & 63;     // float4 col index (64*4 = 256)
  int row = blockIdx.x * 4 + r;
  float tvv = ts[r] - m;
  float4 sv = *reinterpret_cast<const float4*>(&ss[c4 * 4]);
  float4 bv = *reinterpret_cast<const float4*>(&bs[c4 * 4]);
  float4 o;
  o.x = tvv * sv.x + bv.x; o.x = (o.x >= 0.f) ? o.x : NEG_SLOPE * o.x;
  o.y = tvv * sv.y + bv.y; o.y = (o.y >= 0.f) ? o.y : NEG_SLOPE * o.y;
  o.z = tvv * sv.z + bv.z; o.z = (o.z >= 0.f) ? o.z : NEG_SLOPE * o.z;
  o.w = tvv * sv.w + bv.w; o.w = (o.w >= 0.f) ? o.w : NEG_SLOPE * o.w;
  reinterpret_cast<float4*>(out)[(size_t)row * (Dout / 4) + c4] = o;
}

extern "C" void kernel_launch(void* const* d_in, const int* in_sizes, int n_in,
                              void* d_out, int out_size, void* d_ws, size_t ws_size,
                              hipStream_t stream) {
  const float* x      = (const float*)d_in[0];
  const float* alphas = (const float*)d_in[1];
  const float* cA     = (const float*)d_in[2];
  const float* cB     = (const float*)d_in[3];
  // d_in[4] = linear_bias: cancels exactly inside BatchNorm (out - mean).
  const float* gamma  = (const float*)d_in[5];
  const float* beta   = (const float*)d_in[6];
  float* out = (float*)d_out;
  float* ws  = (float*)d_ws;

  float*   Bv       = ws + WS_BV;
  float*   A        = ws + WS_A;
  float*   t        = ws + WS_T;
  double2* partials = reinterpret_cast<double2*>(ws + WS_PART);

  k_synth<<<1 + Din / 256, 256, 0, stream>>>(alphas, cA, cB, A, Bv);
  k_matvec<<<B_ / 8, 512, 0, stream>>>(x, Bv, t, partials);
  k_finish<<<B_ / 4, 256, 0, stream>>>(t, partials, A, gamma, beta, out);
}

// Round 5
// 58.437 us; speedup vs baseline: 1.2578x; 1.0361x over previous
//
#include <hip/hip_runtime.h>

#define BN_EPS 1e-5f
#define NEG_SLOPE 0.2f

constexpr int B_ = 16384;
constexpr int Din = 4096;
constexpr int Dout = 256;
constexpr int D_RANK = 20;
constexpr int NPART = 2048;   // one partial per matvec block

typedef float f4 __attribute__((ext_vector_type(4)));  // native vec type for nontemporal builtins

// ws layout (floats):
// [0, 4096)        : Bv
// [4096, 4352)     : A
// [4352, 20736)    : t (16384)
// [20736, 20992)   : s  (256)  = A*gamma*rsqrt(A^2*var+eps)
// [20992, 21248)   : b2 (256)  = beta - mean*s
// [21248, 29440)   : partials: 2048 x double2 (byte 84992, 16B-aligned)
#define WS_BV 0
#define WS_A 4096
#define WS_T 4352
#define WS_S 20736
#define WS_B2 20992
#define WS_PART 21248

// ---------------- Kernel 1: synthesize A (Dout) and Bv (Din) -----------------
__global__ __launch_bounds__(256) void k_synth(
    const float* __restrict__ alphas, const float* __restrict__ cA,
    const float* __restrict__ cB, float* __restrict__ A, float* __restrict__ Bv) {
  __shared__ float al[D_RANK];
  int tid = threadIdx.x;
  if (tid < D_RANK) al[tid] = alphas[tid];
  __syncthreads();
  if (blockIdx.x == 0) {
    float s = 0.f;
#pragma unroll
    for (int d = 0; d < D_RANK; ++d) s += al[d] * cA[d * Dout + tid];
    A[tid] = s;
  } else {
    int k = (blockIdx.x - 1) * 256 + tid;
    float s = 0.f;
#pragma unroll
    for (int d = 0; d < D_RANK; ++d) s += al[d] * cB[k * D_RANK + d];
    Bv[k] = s;
  }
}

// ---------------- Kernel 2: t = x @ Bv + per-block (sum, sumsq) partial ------
// 512 threads = 8 waves, one row per wave. grid = B_/8 = 2048.
// Bv staged in LDS: x is the ONLY VMEM stream.
__global__ __launch_bounds__(512) void k_matvec(
    const float* __restrict__ x, const float* __restrict__ Bv,
    float* __restrict__ t, double2* __restrict__ partials) {
  __shared__ f4 bvs[Din / 4];   // 16 KiB
  int tid = threadIdx.x;
  const f4* bv = reinterpret_cast<const f4*>(Bv);
  bvs[tid] = bv[tid];
  bvs[tid + 512] = bv[tid + 512];
  __syncthreads();

  int wave = tid >> 6;   // 0..7
  int lane = tid & 63;
  int row = blockIdx.x * 8 + wave;
  const f4* xr = reinterpret_cast<const f4*>(x + (size_t)row * Din);
  float acc0 = 0.f, acc1 = 0.f;
#pragma unroll
  for (int it = 0; it < 8; ++it) {
    f4 xa = __builtin_nontemporal_load(&xr[it * 128 + lane]);
    f4 xb = __builtin_nontemporal_load(&xr[it * 128 + 64 + lane]);
    f4 ba = bvs[it * 128 + lane];
    f4 bb = bvs[it * 128 + 64 + lane];
    acc0 += xa.x * ba.x + xa.y * ba.y + xa.z * ba.z + xa.w * ba.w;
    acc1 += xb.x * bb.x + xb.y * bb.y + xb.z * bb.z + xb.w * bb.w;
  }
  float acc = acc0 + acc1;
#pragma unroll
  for (int off = 32; off > 0; off >>= 1) acc += __shfl_down(acc, off, 64);
  __shared__ float tv[8];
  if (lane == 0) {
    t[row] = acc;
    tv[wave] = acc;
  }
  __syncthreads();
  if (tid == 0) {
    double s = 0.0, q = 0.0;
#pragma unroll
    for (int w = 0; w < 8; ++w) {
      double v = (double)tv[w];
      s += v;
      q += v * v;
    }
    partials[blockIdx.x] = make_double2(s, q);
  }
}

// ---------------- Kernel 3: stats = reduce partials once, fold mean ---------
// single block, 1024 threads. Deterministic fixed-order tree in double.
__global__ __launch_bounds__(1024) void k_stats(
    const double2* __restrict__ partials, const float* __restrict__ A,
    const float* __restrict__ gamma, const float* __restrict__ beta,
    float* __restrict__ s, float* __restrict__ b2) {
  __shared__ double sd[1024];
  __shared__ double sq[1024];
  int tid = threadIdx.x;
  double2 p0 = partials[tid];
  double2 p1 = partials[tid + 1024];
  sd[tid] = p0.x + p1.x;
  sq[tid] = p0.y + p1.y;
  __syncthreads();
  for (int off = 512; off > 0; off >>= 1) {
    if (tid < off) {
      sd[tid] += sd[tid + off];
      sq[tid] += sq[tid + off];
    }
    __syncthreads();
  }
  double mean = sd[0] / (double)B_;
  double var = sq[0] / (double)B_ - mean * mean;  // biased, matches jnp.var
  if (tid < Dout) {
    float a = A[tid];
    float inv = rsqrtf((float)((double)a * (double)a * var) + BN_EPS);
    float sj = a * gamma[tid] * inv;
    s[tid] = sj;
    b2[tid] = beta[tid] - (float)mean * sj;
  }
}

// ---------------- Kernel 4: out = leaky(t[i]*s[j] + b2[j]) -------------------
// pure streaming write: 16 rows per 1024-thread block, grid = B_/16 = 1024.
__global__ __launch_bounds__(1024) void k_finish(
    const float* __restrict__ t, const float* __restrict__ s,
    const float* __restrict__ b2, float* __restrict__ out) {
  __shared__ float ss[Dout];
  __shared__ float bs[Dout];
  __shared__ float ts[16];
  int tid = threadIdx.x;
  if (tid < Dout) {
    ss[tid] = s[tid];
    bs[tid] = b2[tid];
  }
  if (tid < 16) ts[tid] = t[blockIdx.x * 16 + tid];
  __syncthreads();
  int r = tid >> 6;      // row within block (0..15)
  int c4 = tid & 63;     // float4 col index (64*4 = 256)
  int row = blockIdx.x * 16 + r;
  float tvv = ts[r];
  float4 sv = *reinterpret_cast<const float4*>(&ss[c4 * 4]);
  float4 bv = *reinterpret_cast<const float4*>(&bs[c4 * 4]);
  float4 o;
  o.x = tvv * sv.x + bv.x; o.x = (o.x >= 0.f) ? o.x : NEG_SLOPE * o.x;
  o.y = tvv * sv.y + bv.y; o.y = (o.y >= 0.f) ? o.y : NEG_SLOPE * o.y;
  o.z = tvv * sv.z + bv.z; o.z = (o.z >= 0.f) ? o.z : NEG_SLOPE * o.z;
  o.w = tvv * sv.w + bv.w; o.w = (o.w >= 0.f) ? o.w : NEG_SLOPE * o.w;
  reinterpret_cast<float4*>(out)[(size_t)row * (Dout / 4) + c4] = o;
}

extern "C" void kernel_launch(void* const* d_in, const int* in_sizes, int n_in,
                              void* d_out, int out_size, void* d_ws, size_t ws_size,
                              hipStream_t stream) {
  const float* x      = (const float*)d_in[0];
  const float* alphas = (const float*)d_in[1];
  const float* cA     = (const float*)d_in[2];
  const float* cB     = (const float*)d_in[3];
  // d_in[4] = linear_bias: cancels exactly inside BatchNorm (out - mean).
  const float* gamma  = (const float*)d_in[5];
  const float* beta   = (const float*)d_in[6];
  float* out = (float*)d_out;
  float* ws  = (float*)d_ws;

  float*   Bv       = ws + WS_BV;
  float*   A        = ws + WS_A;
  float*   t        = ws + WS_T;
  float*   s        = ws + WS_S;
  float*   b2       = ws + WS_B2;
  double2* partials = reinterpret_cast<double2*>(ws + WS_PART);

  k_synth<<<1 + Din / 256, 256, 0, stream>>>(alphas, cA, cB, A, Bv);
  k_matvec<<<B_ / 8, 512, 0, stream>>>(x, Bv, t, partials);
  k_stats<<<1, 1024, 0, stream>>>(partials, A, gamma, beta, s, b2);
  k_finish<<<B_ / 16, 1024, 0, stream>>>(t, s, b2, out);
}

// Round 6
// 58.405 us; speedup vs baseline: 1.2584x; 1.0005x over previous
//
#include <hip/hip_runtime.h>
#include <hip/hip_cooperative_groups.h>

#define BN_EPS 1e-5f
#define NEG_SLOPE 0.2f

constexpr int B_ = 16384;
constexpr int Din = 4096;
constexpr int Dout = 256;
constexpr int D_RANK = 20;
constexpr int NBLK = 1024;        // cooperative grid (4 blocks/CU on 256 CUs)
constexpr int ROWS_PB = 16;       // B_ / NBLK
constexpr int NPART = 2048;       // fallback path partial count

typedef float f4 __attribute__((ext_vector_type(4)));

// ws layout (floats):
// [0, 4096)        : Bv
// [4096, 4352)     : A
// [4352, 20736)    : t (fallback only)
// [20736, 20992)   : s  (fallback only)
// [20992, 21248)   : b2 (fallback only)
// [21248, 29440)   : partials: up to 2048 x double2 (byte 84992, 16B-aligned)
#define WS_BV 0
#define WS_A 4096
#define WS_T 4352
#define WS_S 20736
#define WS_B2 20992
#define WS_PART 21248

// ============================ FUSED COOPERATIVE PATH =========================
// 1024 blocks x 256 threads, all co-resident (4/CU). Three phases split by
// grid.sync(). Deterministic: every reduction is a fixed-order tree.
__global__ __launch_bounds__(256, 4) void k_fused(
    const float* __restrict__ x, const float* __restrict__ alphas,
    const float* __restrict__ cA, const float* __restrict__ cB,
    const float* __restrict__ gamma, const float* __restrict__ beta,
    float* __restrict__ A_g, float* __restrict__ Bv_g,
    double2* __restrict__ partials, float* __restrict__ out) {
  cooperative_groups::grid_group grid = cooperative_groups::this_grid();
  __shared__ f4 bvs[Din / 4];      // 16 KiB
  __shared__ float t_lds[ROWS_PB];
  __shared__ double sd[256];       // 2 KiB
  __shared__ double sq[256];       // 2 KiB
  __shared__ float ss[Dout];
  __shared__ float bs[Dout];
  __shared__ float al[D_RANK];

  int tid = threadIdx.x;

  // ---- phase 0: synthesize Bv (4 entries per block) and A (block 0) ----
  if (tid < D_RANK) al[tid] = alphas[tid];
  __syncthreads();
  if (tid < 4) {
    int k = blockIdx.x * 4 + tid;
    float s = 0.f;
#pragma unroll
    for (int d = 0; d < D_RANK; ++d) s += al[d] * cB[k * D_RANK + d];
    Bv_g[k] = s;
  }
  if (blockIdx.x == 0) {
    float s = 0.f;
#pragma unroll
    for (int d = 0; d < D_RANK; ++d) s += al[d] * cA[d * Dout + tid];
    A_g[tid] = s;
  }
  grid.sync();

  // ---- phase 1: matvec 16 rows, t in LDS, one double2 partial per block ----
  {
    const f4* bvg = reinterpret_cast<const f4*>(Bv_g);
#pragma unroll
    for (int i = 0; i < 4; ++i) bvs[tid + i * 256] = bvg[tid + i * 256];
    __syncthreads();

    int wave = tid >> 6;   // 0..3
    int lane = tid & 63;
#pragma unroll
    for (int r = 0; r < 4; ++r) {
      int rin = wave * 4 + r;
      int row = blockIdx.x * ROWS_PB + rin;
      const f4* xr = reinterpret_cast<const f4*>(x + (size_t)row * Din);
      float acc0 = 0.f, acc1 = 0.f;
#pragma unroll
      for (int it = 0; it < 8; ++it) {
        f4 xa = __builtin_nontemporal_load(&xr[it * 128 + lane]);
        f4 xb = __builtin_nontemporal_load(&xr[it * 128 + 64 + lane]);
        f4 ba = bvs[it * 128 + lane];
        f4 bb = bvs[it * 128 + 64 + lane];
        acc0 += xa.x * ba.x + xa.y * ba.y + xa.z * ba.z + xa.w * ba.w;
        acc1 += xb.x * bb.x + xb.y * bb.y + xb.z * bb.z + xb.w * bb.w;
      }
      float acc = acc0 + acc1;
#pragma unroll
      for (int off = 32; off > 0; off >>= 1) acc += __shfl_down(acc, off, 64);
      if (lane == 0) t_lds[rin] = acc;
    }
    __syncthreads();
    if (tid == 0) {
      double s = 0.0, q = 0.0;
#pragma unroll
      for (int w = 0; w < ROWS_PB; ++w) {
        double v = (double)t_lds[w];
        s += v;
        q += v * v;
      }
      partials[blockIdx.x] = make_double2(s, q);
    }
  }
  grid.sync();

  // ---- phase 2: every block reduces 1024 partials (fixed order), writes out -
  {
    double ls = 0.0, lq = 0.0;
#pragma unroll
    for (int i = 0; i < NBLK / 256; ++i) {
      double2 p = partials[tid + i * 256];
      ls += p.x;
      lq += p.y;
    }
    sd[tid] = ls;
    sq[tid] = lq;
    __syncthreads();
    for (int off = 128; off > 0; off >>= 1) {
      if (tid < off) {
        sd[tid] += sd[tid + off];
        sq[tid] += sq[tid + off];
      }
      __syncthreads();
    }
    double mean = sd[0] / (double)B_;
    double var = sq[0] / (double)B_ - mean * mean;  // biased, matches jnp.var
    float a = A_g[tid];
    float inv = rsqrtf((float)((double)a * (double)a * var) + BN_EPS);
    float sj = a * gamma[tid] * inv;
    ss[tid] = sj;
    bs[tid] = beta[tid] - (float)mean * sj;
    __syncthreads();

    f4* outv = reinterpret_cast<f4*>(out);
#pragma unroll
    for (int j = 0; j < 4; ++j) {
      int idx = j * 256 + tid;   // 0..1023 = 16 rows x 64 f4
      int rin = idx >> 6;
      int c4 = idx & 63;
      int row = blockIdx.x * ROWS_PB + rin;
      float tv = t_lds[rin];
      f4 sv = *reinterpret_cast<const f4*>(&ss[c4 * 4]);
      f4 bv = *reinterpret_cast<const f4*>(&bs[c4 * 4]);
      f4 o;
      o.x = tv * sv.x + bv.x; o.x = (o.x >= 0.f) ? o.x : NEG_SLOPE * o.x;
      o.y = tv * sv.y + bv.y; o.y = (o.y >= 0.f) ? o.y : NEG_SLOPE * o.y;
      o.z = tv * sv.z + bv.z; o.z = (o.z >= 0.f) ? o.z : NEG_SLOPE * o.z;
      o.w = tv * sv.w + bv.w; o.w = (o.w >= 0.f) ? o.w : NEG_SLOPE * o.w;
      outv[(size_t)row * (Dout / 4) + c4] = o;
    }
  }
}

// ============================ FALLBACK 4-KERNEL PATH =========================
__global__ __launch_bounds__(256) void k_synth(
    const float* __restrict__ alphas, const float* __restrict__ cA,
    const float* __restrict__ cB, float* __restrict__ A, float* __restrict__ Bv) {
  __shared__ float al[D_RANK];
  int tid = threadIdx.x;
  if (tid < D_RANK) al[tid] = alphas[tid];
  __syncthreads();
  if (blockIdx.x == 0) {
    float s = 0.f;
#pragma unroll
    for (int d = 0; d < D_RANK; ++d) s += al[d] * cA[d * Dout + tid];
    A[tid] = s;
  } else {
    int k = (blockIdx.x - 1) * 256 + tid;
    float s = 0.f;
#pragma unroll
    for (int d = 0; d < D_RANK; ++d) s += al[d] * cB[k * D_RANK + d];
    Bv[k] = s;
  }
}

__global__ __launch_bounds__(512) void k_matvec(
    const float* __restrict__ x, const float* __restrict__ Bv,
    float* __restrict__ t, double2* __restrict__ partials) {
  __shared__ f4 bvs[Din / 4];
  int tid = threadIdx.x;
  const f4* bv = reinterpret_cast<const f4*>(Bv);
  bvs[tid] = bv[tid];
  bvs[tid + 512] = bv[tid + 512];
  __syncthreads();
  int wave = tid >> 6;
  int lane = tid & 63;
  int row = blockIdx.x * 8 + wave;
  const f4* xr = reinterpret_cast<const f4*>(x + (size_t)row * Din);
  float acc0 = 0.f, acc1 = 0.f;
#pragma unroll
  for (int it = 0; it < 8; ++it) {
    f4 xa = __builtin_nontemporal_load(&xr[it * 128 + lane]);
    f4 xb = __builtin_nontemporal_load(&xr[it * 128 + 64 + lane]);
    f4 ba = bvs[it * 128 + lane];
    f4 bb = bvs[it * 128 + 64 + lane];
    acc0 += xa.x * ba.x + xa.y * ba.y + xa.z * ba.z + xa.w * ba.w;
    acc1 += xb.x * bb.x + xb.y * bb.y + xb.z * bb.z + xb.w * bb.w;
  }
  float acc = acc0 + acc1;
#pragma unroll
  for (int off = 32; off > 0; off >>= 1) acc += __shfl_down(acc, off, 64);
  __shared__ float tv[8];
  if (lane == 0) {
    t[row] = acc;
    tv[wave] = acc;
  }
  __syncthreads();
  if (tid == 0) {
    double s = 0.0, q = 0.0;
#pragma unroll
    for (int w = 0; w < 8; ++w) {
      double v = (double)tv[w];
      s += v;
      q += v * v;
    }
    partials[blockIdx.x] = make_double2(s, q);
  }
}

__global__ __launch_bounds__(1024) void k_stats(
    const double2* __restrict__ partials, const float* __restrict__ A,
    const float* __restrict__ gamma, const float* __restrict__ beta,
    float* __restrict__ s, float* __restrict__ b2) {
  __shared__ double sd[1024];
  __shared__ double sq[1024];
  int tid = threadIdx.x;
  double2 p0 = partials[tid];
  double2 p1 = partials[tid + 1024];
  sd[tid] = p0.x + p1.x;
  sq[tid] = p0.y + p1.y;
  __syncthreads();
  for (int off = 512; off > 0; off >>= 1) {
    if (tid < off) {
      sd[tid] += sd[tid + off];
      sq[tid] += sq[tid + off];
    }
    __syncthreads();
  }
  double mean = sd[0] / (double)B_;
  double var = sq[0] / (double)B_ - mean * mean;
  if (tid < Dout) {
    float a = A[tid];
    float inv = rsqrtf((float)((double)a * (double)a * var) + BN_EPS);
    float sj = a * gamma[tid] * inv;
    s[tid] = sj;
    b2[tid] = beta[tid] - (float)mean * sj;
  }
}

__global__ __launch_bounds__(1024) void k_finish(
    const float* __restrict__ t, const float* __restrict__ s,
    const float* __restrict__ b2, float* __restrict__ out) {
  __shared__ float ss[Dout];
  __shared__ float bs[Dout];
  __shared__ float ts[16];
  int tid = threadIdx.x;
  if (tid < Dout) {
    ss[tid] = s[tid];
    bs[tid] = b2[tid];
  }
  if (tid < 16) ts[tid] = t[blockIdx.x * 16 + tid];
  __syncthreads();
  int r = tid >> 6;
  int c4 = tid & 63;
  int row = blockIdx.x * 16 + r;
  float tvv = ts[r];
  float4 sv = *reinterpret_cast<const float4*>(&ss[c4 * 4]);
  float4 bv = *reinterpret_cast<const float4*>(&bs[c4 * 4]);
  float4 o;
  o.x = tvv * sv.x + bv.x; o.x = (o.x >= 0.f) ? o.x : NEG_SLOPE * o.x;
  o.y = tvv * sv.y + bv.y; o.y = (o.y >= 0.f) ? o.y : NEG_SLOPE * o.y;
  o.z = tvv * sv.z + bv.z; o.z = (o.z >= 0.f) ? o.z : NEG_SLOPE * o.z;
  o.w = tvv * sv.w + bv.w; o.w = (o.w >= 0.f) ? o.w : NEG_SLOPE * o.w;
  reinterpret_cast<float4*>(out)[(size_t)row * (Dout / 4) + c4] = o;
}

extern "C" void kernel_launch(void* const* d_in, const int* in_sizes, int n_in,
                              void* d_out, int out_size, void* d_ws, size_t ws_size,
                              hipStream_t stream) {
  const float* x      = (const float*)d_in[0];
  const float* alphas = (const float*)d_in[1];
  const float* cA     = (const float*)d_in[2];
  const float* cB     = (const float*)d_in[3];
  // d_in[4] = linear_bias: cancels exactly inside BatchNorm (out - mean).
  const float* gamma  = (const float*)d_in[5];
  const float* beta   = (const float*)d_in[6];
  float* out = (float*)d_out;
  float* ws  = (float*)d_ws;

  float*   Bv       = ws + WS_BV;
  float*   A        = ws + WS_A;
  float*   t        = ws + WS_T;
  float*   s        = ws + WS_S;
  float*   b2       = ws + WS_B2;
  double2* partials = reinterpret_cast<double2*>(ws + WS_PART);

  // Cooperative path requires all 1024 blocks co-resident (>=4 blocks/CU).
  int maxb = 0;
  hipError_t qerr = hipOccupancyMaxActiveBlocksPerMultiprocessor(
      &maxb, reinterpret_cast<const void*>(k_fused), 256, 0);
  bool coop = (qerr == hipSuccess) && (maxb >= NBLK / 256);

  if (coop) {
    void* args[] = {(void*)&x, (void*)&alphas, (void*)&cA, (void*)&cB,
                    (void*)&gamma, (void*)&beta, (void*)&A, (void*)&Bv,
                    (void*)&partials, (void*)&out};
    hipError_t lerr = hipLaunchCooperativeKernel(
        reinterpret_cast<const void*>(k_fused), dim3(NBLK), dim3(256), args, 0,
        stream);
    if (lerr == hipSuccess) return;
  }

  // Fallback: proven 4-kernel path.
  k_synth<<<1 + Din / 256, 256, 0, stream>>>(alphas, cA, cB, A, Bv);
  k_matvec<<<B_ / 8, 512, 0, stream>>>(x, Bv, t, partials);
  k_stats<<<1, 1024, 0, stream>>>(partials, A, gamma, beta, s, b2);
  k_finish<<<B_ / 16, 1024, 0, stream>>>(t, s, b2, out);
}